// Round 11
// baseline (167.103 us; speedup 1.0000x reference)
//
#include <hip/hip_runtime.h>
#include <math.h>

#define NB 2048
#define NS 200
#define ND 128

typedef __attribute__((ext_vector_type(8))) short bf16x8;
typedef __attribute__((ext_vector_type(4))) float f32x4;

// LDS layout (u32 units). W1 planes: unpadded 64 rows x 256 B, chunk-swizzled
// p = (k + h) & 15  ->  conflict-free ds_read_b128, imm-offset addressing.
#define U_W1    0                  // 8192 u32 = 32768 B (hi @0, lo @16384; pass-2 partials alias)
#define U_Q     8192               // 128 f32
#define U_BIAS  8320               // 64 f32
#define U_B2    8384               // 32 f32
#define U_W3    8416               // 32 f32
#define U_SC    8448               // 2 x 208 f32
#define U_WB    8864               // 2 x 208 f32
#define U_WRED  9280               // 16 f32
#define U_BP    9296               // 260 f32 (4 groups x 65)
#define U_TOTAL 9556               // 38224 B -> 4 blocks/CU

union CvtU4 { unsigned int u[4]; bf16x8 v; };

__device__ __forceinline__ unsigned int permhi(unsigned int a, unsigned int b) {
    // hi16(a)<<16 | hi16(b)
    return __builtin_amdgcn_perm(a, b, 0x07060302u);
}
__device__ __forceinline__ unsigned int permlo(unsigned int a, unsigned int b) {
    // lo16(a)<<16 | lo16(b)
    return __builtin_amdgcn_perm(a, b, 0x05040100u);
}

extern "C" __global__ void __launch_bounds__(256, 4)
tdra_main(const float* __restrict__ query,
          const float* __restrict__ keys,
          const int*   __restrict__ kmask,
          const float* __restrict__ W1,
          const float* __restrict__ b1w,
          const float* __restrict__ a1p,
          const float* __restrict__ W2,
          const float* __restrict__ b2,
          const float* __restrict__ a2p,
          const float* __restrict__ W3,
          const float* __restrict__ b3p,
          float* __restrict__ out)
{
    __shared__ __align__(16) unsigned int smem[U_TOTAL];
    char*  w1base = (char*)(smem + U_W1);
    float* qf    = (float*)(smem + U_Q);
    float* biasE = (float*)(smem + U_BIAS);
    float* b2f   = (float*)(smem + U_B2);
    float* w3f   = (float*)(smem + U_W3);
    float* scf   = (float*)(smem + U_SC);
    float* wbf   = (float*)(smem + U_WB);
    float* wred  = (float*)(smem + U_WRED);
    float* bpf   = (float*)(smem + U_BP);

    const int tid = threadIdx.x;
    const int b0  = blockIdx.x * 2;
    const float a1 = a1p[0];
    const float a2 = a2p[0];
    const float b3 = b3p[0];

    const int wv = tid >> 6;
    const int c  = tid & 15;
    const int G  = (tid >> 4) & 3;

    // swizzled read addresses: chunk k=4dt+G of row r=16ht+c stored at p=(k+r)&15
    int adt[4];
    #pragma unroll
    for (int dt = 0; dt < 4; ++dt)
        adt[dt] = c * 256 + ((4 * dt + G + c) & 15) * 16;

    // preload masks for both batches (hide latency under phase 0)
    int mk0 = 0, mk1 = 0;
    if (tid < NS) {
        mk0 = kmask[(size_t)b0 * NS + tid];
        mk1 = kmask[(size_t)(b0 + 1) * NS + tid];
    }

    // ---------- Phase A (once): b2, W3 staging + A2 fragments ----------
    if (tid < 32)       b2f[tid] = b2[tid];
    else if (tid < 64)  w3f[tid - 32] = W3[tid - 32];

    bf16x8 A2h[2][2], A2l[2][2];
    #pragma unroll
    for (int jt = 0; jt < 2; ++jt)
        #pragma unroll
        for (int kt = 0; kt < 2; ++kt)
            #pragma unroll
            for (int e = 0; e < 8; ++e) {
                float x = W2[(kt * 32 + 8 * G + e) * 32 + jt * 16 + c];
                unsigned int u  = __float_as_uint(x);
                unsigned int hb = u & 0xFFFF0000u;
                float lof = x - __uint_as_float(hb);
                A2h[jt][kt][e] = (short)(u >> 16);
                A2l[jt][kt][e] = (short)(__float_as_uint(lof) >> 16);
            }

    // ---------- per-batch: build + main ----------
    #pragma unroll 1
    for (int bb = 0; bb < 2; ++bb) {
        const int bme = b0 + bb;

        if (tid < 32) {
            float4 qv = *(const float4*)(query + (size_t)bme * ND + tid * 4);
            *(float4*)(qf + tid * 4) = qv;
        }
        __syncthreads();

        // build W1 planes = split(W1a+W1d+q*W1c), swizzled; bias partials
        {
            int h = tid & 63, dg = tid >> 6;
            #pragma unroll 2
            for (int i = 0; i < 8; ++i) {
                int dblk = dg * 8 + i;          // 0..31, 4 d each
                unsigned int hp[2], lp[2];
                #pragma unroll
                for (int jp = 0; jp < 2; ++jp) {
                    int d0 = dblk * 4 + 2 * jp;
                    float x0 = W1[d0 * 64 + h] + W1[24576 + d0 * 64 + h]
                             + qf[d0] * W1[16384 + d0 * 64 + h];
                    float x1 = W1[(d0 + 1) * 64 + h] + W1[24576 + (d0 + 1) * 64 + h]
                             + qf[d0 + 1] * W1[16384 + (d0 + 1) * 64 + h];
                    unsigned int u0 = __float_as_uint(x0), u1 = __float_as_uint(x1);
                    hp[jp] = permhi(u1, u0);
                    float l0 = x0 - __uint_as_float(u0 & 0xFFFF0000u);
                    float l1 = x1 - __uint_as_float(u1 & 0xFFFF0000u);
                    lp[jp] = permhi(__float_as_uint(l1), __float_as_uint(l0));
                }
                int k = dblk >> 1;
                int p = (k + h) & 15;
                int byteoff = h * 256 + p * 16 + (dblk & 1) * 8;
                *(uint2*)(w1base + byteoff)         = make_uint2(hp[0], hp[1]);
                *(uint2*)(w1base + 16384 + byteoff) = make_uint2(lp[0], lp[1]);
            }
            // bias partials: q @ (W1b - W1d), 4 groups x 32 d
            const float* pb = W1 + (size_t)(128 + dg * 32) * 64 + h;
            const float* pd = W1 + (size_t)(384 + dg * 32) * 64 + h;
            float pacc = 0.f;
            #pragma unroll 8
            for (int i = 0; i < 32; ++i)
                pacc = fmaf(qf[dg * 32 + i], pb[i * 64] - pd[i * 64], pacc);
            bpf[dg * 65 + h] = pacc;
        }
        __syncthreads();
        if (tid < 64)
            biasE[tid] = b1w[tid] + bpf[tid] + bpf[65 + tid]
                       + bpf[130 + tid] + bpf[195 + tid];
        __syncthreads();

        // main: wave wv owns s-tiles st = wv, wv+4, wv+8, (wv+12)
        #pragma unroll 1
        for (int st = wv; st < 13; st += 4) {
            const int rr = st * 16 + c;
            int row_ld = rr < 199 ? rr : 199;
            const float* kp = keys + ((size_t)bme * NS + row_ld) * ND + 8 * G;

            // keys f32 -> B1 hi/lo frags (staggered halves, perm-packed)
            bf16x8 B1h[4], B1l[4];
            #pragma unroll
            for (int half = 0; half < 2; ++half) {
                float4 xs[4];
                #pragma unroll
                for (int q_ = 0; q_ < 2; ++q_) {
                    xs[2 * q_]     = *(const float4*)(kp + (2 * half + q_) * 32);
                    xs[2 * q_ + 1] = *(const float4*)(kp + (2 * half + q_) * 32 + 4);
                }
                #pragma unroll
                for (int q_ = 0; q_ < 2; ++q_) {
                    int dt = 2 * half + q_;
                    float fe[8] = {xs[2*q_].x, xs[2*q_].y, xs[2*q_].z, xs[2*q_].w,
                                   xs[2*q_+1].x, xs[2*q_+1].y, xs[2*q_+1].z, xs[2*q_+1].w};
                    CvtU4 H, L;
                    #pragma unroll
                    for (int j = 0; j < 4; ++j) {
                        unsigned int u0 = __float_as_uint(fe[2 * j]);
                        unsigned int u1 = __float_as_uint(fe[2 * j + 1]);
                        H.u[j] = permhi(u1, u0);
                        float l0 = fe[2 * j]     - __uint_as_float(u0 & 0xFFFF0000u);
                        float l1 = fe[2 * j + 1] - __uint_as_float(u1 & 0xFFFF0000u);
                        L.u[j] = permhi(__float_as_uint(l1), __float_as_uint(l0));
                    }
                    B1h[dt] = H.v;
                    B1l[dt] = L.v;
                }
            }

            // GEMM1': acc1[ht] = bias + W1eff^T x K^T (swizzled imm-offset reads)
            f32x4 acc1[4];
            #pragma unroll
            for (int ht = 0; ht < 4; ++ht)
                acc1[ht] = *(const f32x4*)(biasE + 16 * ht + 4 * G);
            #pragma unroll
            for (int dt = 0; dt < 4; ++dt) {
                #pragma unroll
                for (int ht = 0; ht < 4; ++ht) {
                    const char* pa = w1base + adt[dt] + ht * 4096;
                    bf16x8 A1h = *(const bf16x8*)(pa);
                    bf16x8 A1l = *(const bf16x8*)(pa + 16384);
                    acc1[ht] = __builtin_amdgcn_mfma_f32_16x16x32_bf16(A1h, B1h[dt], acc1[ht], 0, 0, 0);
                    acc1[ht] = __builtin_amdgcn_mfma_f32_16x16x32_bf16(A1h, B1l[dt], acc1[ht], 0, 0, 0);
                    acc1[ht] = __builtin_amdgcn_mfma_f32_16x16x32_bf16(A1l, B1h[dt], acc1[ht], 0, 0, 0);
                }
            }

            // PReLU -> packed (lo<<16 | hi) h1
            unsigned int p[4][4];
            #pragma unroll
            for (int ht = 0; ht < 4; ++ht)
                #pragma unroll
                for (int r = 0; r < 4; ++r) {
                    float v = acc1[ht][r];
                    v = fmaxf(v, 0.f) + a1 * fminf(v, 0.f);
                    unsigned int u = __float_as_uint(v);
                    float lof = v - __uint_as_float(u & 0xFFFF0000u);
                    p[ht][r] = permhi(__float_as_uint(lof), u);
                }

            // GEMM2': shfl-transpose h1 into B2 frags; acc2 init with b2
            f32x4 acc2[2];
            acc2[0] = *(const f32x4*)(b2f + 4 * G);
            acc2[1] = *(const f32x4*)(b2f + 16 + 4 * G);
            const int srcbase = ((tid & 16) ? 32 : 0) + c;
            #pragma unroll
            for (int kt = 0; kt < 2; ++kt) {
                unsigned int q[8];
                #pragma unroll
                for (int half = 0; half < 2; ++half) {
                    int src = srcbase + half * 16;
                    #pragma unroll
                    for (int r = 0; r < 4; ++r) {
                        unsigned int v0 = (unsigned int)__shfl((int)p[2 * kt][r], src, 64);
                        unsigned int v1 = (unsigned int)__shfl((int)p[2 * kt + 1][r], src, 64);
                        q[half * 4 + r] = (tid & 32) ? v1 : v0;
                    }
                }
                CvtU4 BH, BL;
                #pragma unroll
                for (int j = 0; j < 4; ++j) {
                    BH.u[j] = permlo(q[2 * j + 1], q[2 * j]);
                    BL.u[j] = permhi(q[2 * j + 1], q[2 * j]);
                }
                #pragma unroll
                for (int jt = 0; jt < 2; ++jt) {
                    acc2[jt] = __builtin_amdgcn_mfma_f32_16x16x32_bf16(A2h[jt][kt], BH.v, acc2[jt], 0, 0, 0);
                    acc2[jt] = __builtin_amdgcn_mfma_f32_16x16x32_bf16(A2h[jt][kt], BL.v, acc2[jt], 0, 0, 0);
                    acc2[jt] = __builtin_amdgcn_mfma_f32_16x16x32_bf16(A2l[jt][kt], BH.v, acc2[jt], 0, 0, 0);
                }
            }

            // scores: PReLU + W3-dot in-lane, xor-reduce
            float sv = 0.f;
            #pragma unroll
            for (int jt = 0; jt < 2; ++jt)
                #pragma unroll
                for (int r = 0; r < 4; ++r) {
                    float v = acc2[jt][r];
                    v = fmaxf(v, 0.f) + a2 * fminf(v, 0.f);
                    sv = fmaf(v, w3f[jt * 16 + 4 * G + r], sv);
                }
            sv += __shfl_xor(sv, 16, 64);
            sv += __shfl_xor(sv, 32, 64);
            if ((tid & 48) == 0 && rr < NS) scf[bb * 208 + rr] = sv + b3;
        }
        __syncthreads();
    }

    // ---------- combined epilogue: decay + mask + softmax (both batches) ----
    float dk = __expf(0.1f * (float)(tid - (NS - 1)));
    float s0 = -INFINITY, s1 = -INFINITY;
    if (tid < NS) {
        if (mk0) s0 = scf[tid] * dk;
        if (mk1) s1 = scf[208 + tid] * dk;
    }
    const int wid = tid >> 6, lane = tid & 63;
    float m0 = s0, m1 = s1;
    #pragma unroll
    for (int o = 32; o > 0; o >>= 1) {
        m0 = fmaxf(m0, __shfl_xor(m0, o, 64));
        m1 = fmaxf(m1, __shfl_xor(m1, o, 64));
    }
    if (lane == 0) { wred[wid] = m0; wred[4 + wid] = m1; }
    __syncthreads();
    float M0 = fmaxf(fmaxf(wred[0], wred[1]), fmaxf(wred[2], wred[3]));
    float M1 = fmaxf(fmaxf(wred[4], wred[5]), fmaxf(wred[6], wred[7]));
    float e0 = (M0 > -INFINITY && s0 > -INFINITY) ? __expf(s0 - M0) : 0.f;
    float e1 = (M1 > -INFINITY && s1 > -INFINITY) ? __expf(s1 - M1) : 0.f;
    float t0 = e0, t1 = e1;
    #pragma unroll
    for (int o = 32; o > 0; o >>= 1) {
        t0 += __shfl_xor(t0, o, 64);
        t1 += __shfl_xor(t1, o, 64);
    }
    if (lane == 0) { wred[8 + wid] = t0; wred[12 + wid] = t1; }
    __syncthreads();
    float S0 = wred[8] + wred[9] + wred[10] + wred[11];
    float S1 = wred[12] + wred[13] + wred[14] + wred[15];
    float w0 = (S0 > 0.f) ? (e0 / S0) : 0.f;
    float w1 = (S1 > 0.f) ? (e1 / S1) : 0.f;
    if (tid < NS) {
        wbf[tid] = w0;
        wbf[208 + tid] = w1;
        out[(size_t)NB * ND + (size_t)b0 * NS + tid] = w0;
        out[(size_t)NB * ND + (size_t)(b0 + 1) * NS + tid] = w1;
    }
    __syncthreads();

    // ---------- pass 2: weighted_sum = w @ keys, both batches ----------
    float* part = (float*)(smem + U_W1);   // aliases dead W1 planes: 2048 f32
    {
        const int dq = tid & 31, sg = tid >> 3 >> 2;  // sg = tid>>5: 8 groups x 25 rows
        #pragma unroll 1
        for (int bb = 0; bb < 2; ++bb) {
            const float* kb = keys + ((size_t)(b0 + bb) * NS + sg * 25) * ND + dq * 4;
            float ax = 0.f, ay = 0.f, az = 0.f, aw = 0.f;
            #pragma unroll 5
            for (int i = 0; i < 25; ++i) {
                float ww = wbf[bb * 208 + sg * 25 + i];
                float4 kv = *(const float4*)(kb + (size_t)i * ND);
                ax = fmaf(ww, kv.x, ax);
                ay = fmaf(ww, kv.y, ay);
                az = fmaf(ww, kv.z, az);
                aw = fmaf(ww, kv.w, aw);
            }
            *(float4*)(part + bb * 1024 + sg * 128 + dq * 4) = make_float4(ax, ay, az, aw);
        }
    }
    __syncthreads();
    if (tid < 128) {
        float s = 0.f;
        #pragma unroll
        for (int g = 0; g < 8; ++g) s += part[g * 128 + tid];
        out[(size_t)b0 * ND + tid] = s;
    } else {
        int d = tid - 128;
        float s = 0.f;
        #pragma unroll
        for (int g = 0; g < 8; ++g) s += part[1024 + g * 128 + d];
        out[(size_t)(b0 + 1) * ND + d] = s;
    }
}

extern "C" void kernel_launch(void* const* d_in, const int* in_sizes, int n_in,
                              void* d_out, int out_size, void* d_ws, size_t ws_size,
                              hipStream_t stream) {
    (void)in_sizes; (void)n_in; (void)d_ws; (void)ws_size; (void)out_size;
    const float* query = (const float*)d_in[0];
    const float* keys  = (const float*)d_in[1];
    const int*   kmask = (const int*)d_in[2];
    const float* W1 = (const float*)d_in[3];
    const float* b1 = (const float*)d_in[4];
    const float* a1 = (const float*)d_in[5];
    const float* W2 = (const float*)d_in[6];
    const float* b2 = (const float*)d_in[7];
    const float* a2 = (const float*)d_in[8];
    const float* W3 = (const float*)d_in[9];
    const float* b3 = (const float*)d_in[10];
    float* out = (float*)d_out;

    hipLaunchKernelGGL(tdra_main, dim3(NB / 2), dim3(256), 0, stream,
                       query, keys, kmask, W1, b1, a1, W2, b2, a2, W3, b3, out);
}

// Round 12
// 106.409 us; speedup vs baseline: 1.5704x; 1.5704x over previous
//
#include <hip/hip_runtime.h>
#include <math.h>

#define NB 2048
#define NS 200
#define ND 128

typedef __attribute__((ext_vector_type(8))) short bf16x8;
typedef __attribute__((ext_vector_type(4))) float f32x4;

// LDS layout (u32 units)
#define U_W1HI  0                  // 64 x 136 u16 = 4352 u32 (aliased by pass-2 partials)
#define U_W1LO  4352               // 4352 u32
#define U_Q     8704               // 128 f32
#define U_BIAS  8832               // 64 f32
#define U_B2    8896               // 32 f32
#define U_W3    8928               // 32 f32
#define U_SC    8960               // 208 f32
#define U_WB    9168               // 208 f32
#define U_WRED  9376               // 8 f32
#define U_BP    9384               // 260 f32 (phase0 bias partials)
#define U_TOTAL 9644               // 38576 B -> 4 blocks/CU

union CvtU4 { unsigned int u[4]; bf16x8 v; };

__device__ __forceinline__ unsigned int permhi(unsigned int a, unsigned int b) {
    // hi16(a)<<16 | hi16(b)
    return __builtin_amdgcn_perm(a, b, 0x07060302u);
}
__device__ __forceinline__ unsigned int permlo(unsigned int a, unsigned int b) {
    // lo16(a)<<16 | lo16(b)
    return __builtin_amdgcn_perm(a, b, 0x05040100u);
}

extern "C" __global__ void __launch_bounds__(256, 4)
tdra_main(const float* __restrict__ query,
          const float* __restrict__ keys,
          const int*   __restrict__ kmask,
          const float* __restrict__ W1,
          const float* __restrict__ b1,
          const float* __restrict__ a1p,
          const float* __restrict__ W2,
          const float* __restrict__ b2,
          const float* __restrict__ a2p,
          const float* __restrict__ W3,
          const float* __restrict__ b3p,
          float* __restrict__ out)
{
    __shared__ __align__(16) unsigned int smem[U_TOTAL];
    unsigned short* W1hi = (unsigned short*)(smem + U_W1HI);
    unsigned short* W1lo = (unsigned short*)(smem + U_W1LO);
    float* qf    = (float*)(smem + U_Q);
    float* biasE = (float*)(smem + U_BIAS);
    float* b2f   = (float*)(smem + U_B2);
    float* w3f   = (float*)(smem + U_W3);
    float* scf   = (float*)(smem + U_SC);
    float* wbf   = (float*)(smem + U_WB);
    float* wred  = (float*)(smem + U_WRED);
    float* bpf   = (float*)(smem + U_BP);

    const int tid = threadIdx.x;
    const int b   = blockIdx.x;
    const float a1 = a1p[0];
    const float a2 = a2p[0];
    const float b3 = b3p[0];

    const int wv = tid >> 6;
    const int c  = tid & 15;
    const int G  = (tid >> 4) & 3;

    // ---------- Phase 0a: q, b2, W3 staging ----------
    if (tid < 32) {
        float4 qv = *(const float4*)(query + (size_t)b * ND + tid * 4);
        *(float4*)(qf + tid * 4) = qv;
    } else if (tid < 64) {
        b2f[tid - 32] = b2[tid - 32];
    } else if (tid < 96) {
        w3f[tid - 64] = W3[tid - 64];
    }

    // A2 = W2^T fragments straight from global (st-invariant, L2-hit)
    bf16x8 A2h[2][2], A2l[2][2];
    #pragma unroll
    for (int jt = 0; jt < 2; ++jt)
        #pragma unroll
        for (int kt = 0; kt < 2; ++kt)
            #pragma unroll
            for (int e = 0; e < 8; ++e) {
                float x = W2[(kt * 32 + 8 * G + e) * 32 + jt * 16 + c];
                unsigned int u  = __float_as_uint(x);
                unsigned int hb = u & 0xFFFF0000u;
                float lof = x - __uint_as_float(hb);
                A2h[jt][kt][e] = (short)(u >> 16);
                A2l[jt][kt][e] = (short)(__float_as_uint(lof) >> 16);
            }
    __syncthreads();

    // ---------- Phase 0b: W1 planes = split(W1a+W1d+q*W1c); bias partials ----
    {
        int h = tid & 63, dg = tid >> 6;
        #pragma unroll 2
        for (int i = 0; i < 8; ++i) {
            int dblk = dg * 8 + i;
            unsigned int hp[2], lp[2];
            #pragma unroll
            for (int jp = 0; jp < 2; ++jp) {
                int d0 = dblk * 4 + 2 * jp;
                float x0 = W1[d0 * 64 + h] + W1[24576 + d0 * 64 + h]
                         + qf[d0] * W1[16384 + d0 * 64 + h];
                float x1 = W1[(d0 + 1) * 64 + h] + W1[24576 + (d0 + 1) * 64 + h]
                         + qf[d0 + 1] * W1[16384 + (d0 + 1) * 64 + h];
                unsigned int u0 = __float_as_uint(x0), u1 = __float_as_uint(x1);
                hp[jp] = permhi(u1, u0);
                float l0 = x0 - __uint_as_float(u0 & 0xFFFF0000u);
                float l1 = x1 - __uint_as_float(u1 & 0xFFFF0000u);
                lp[jp] = permhi(__float_as_uint(l1), __float_as_uint(l0));
            }
            *(uint2*)(W1hi + h * 136 + dblk * 4) = make_uint2(hp[0], hp[1]);
            *(uint2*)(W1lo + h * 136 + dblk * 4) = make_uint2(lp[0], lp[1]);
        }
        int qt = dg;
        const float* pb = W1 + (size_t)(128 + qt * 32) * 64 + h;
        const float* pd = W1 + (size_t)(384 + qt * 32) * 64 + h;
        float p = 0.f;
        #pragma unroll 8
        for (int i = 0; i < 32; ++i)
            p = fmaf(qf[qt * 32 + i], pb[i * 64] - pd[i * 64], p);
        bpf[qt * 65 + h] = p;
    }
    __syncthreads();
    if (tid < 64)
        biasE[tid] = b1[tid] + bpf[tid] + bpf[65 + tid] + bpf[130 + tid] + bpf[195 + tid];
    __syncthreads();

    // ---------- Main: wave wv owns s-tiles st = wv, wv+4, wv+8, (wv+12) ------
    #pragma unroll 1
    for (int st = wv; st < 13; st += 4) {
        const int rr = st * 16 + c;
        int row_ld = rr < 199 ? rr : 199;
        const float* kp = keys + ((size_t)b * NS + row_ld) * ND + 8 * G;

        // keys f32 -> B1 hi/lo frags (staggered halves, perm-packed)
        bf16x8 B1h[4], B1l[4];
        #pragma unroll
        for (int half = 0; half < 2; ++half) {
            float4 xs[4];
            #pragma unroll
            for (int q_ = 0; q_ < 2; ++q_) {
                xs[2 * q_]     = *(const float4*)(kp + (2 * half + q_) * 32);
                xs[2 * q_ + 1] = *(const float4*)(kp + (2 * half + q_) * 32 + 4);
            }
            #pragma unroll
            for (int q_ = 0; q_ < 2; ++q_) {
                int dt = 2 * half + q_;
                float fe[8] = {xs[2*q_].x, xs[2*q_].y, xs[2*q_].z, xs[2*q_].w,
                               xs[2*q_+1].x, xs[2*q_+1].y, xs[2*q_+1].z, xs[2*q_+1].w};
                CvtU4 H, L;
                #pragma unroll
                for (int j = 0; j < 4; ++j) {
                    unsigned int u0 = __float_as_uint(fe[2 * j]);
                    unsigned int u1 = __float_as_uint(fe[2 * j + 1]);
                    H.u[j] = permhi(u1, u0);
                    float l0 = fe[2 * j]     - __uint_as_float(u0 & 0xFFFF0000u);
                    float l1 = fe[2 * j + 1] - __uint_as_float(u1 & 0xFFFF0000u);
                    L.u[j] = permhi(__float_as_uint(l1), __float_as_uint(l0));
                }
                B1h[dt] = H.v;
                B1l[dt] = L.v;
            }
        }

        // GEMM1': acc1[ht] = bias + W1eff^T x K^T
        f32x4 acc1[4];
        #pragma unroll
        for (int ht = 0; ht < 4; ++ht)
            acc1[ht] = *(const f32x4*)(biasE + 16 * ht + 4 * G);
        #pragma unroll
        for (int dt = 0; dt < 4; ++dt) {
            #pragma unroll
            for (int ht = 0; ht < 4; ++ht) {
                int idx = (16 * ht + c) * 136 + 32 * dt + 8 * G;
                bf16x8 A1h = *(const bf16x8*)(W1hi + idx);
                bf16x8 A1l = *(const bf16x8*)(W1lo + idx);
                acc1[ht] = __builtin_amdgcn_mfma_f32_16x16x32_bf16(A1h, B1h[dt], acc1[ht], 0, 0, 0);
                acc1[ht] = __builtin_amdgcn_mfma_f32_16x16x32_bf16(A1h, B1l[dt], acc1[ht], 0, 0, 0);
                acc1[ht] = __builtin_amdgcn_mfma_f32_16x16x32_bf16(A1l, B1h[dt], acc1[ht], 0, 0, 0);
            }
        }

        // PReLU -> packed (lo<<16 | hi) h1
        unsigned int p[4][4];
        #pragma unroll
        for (int ht = 0; ht < 4; ++ht)
            #pragma unroll
            for (int r = 0; r < 4; ++r) {
                float v = acc1[ht][r];
                v = fmaxf(v, 0.f) + a1 * fminf(v, 0.f);
                unsigned int u = __float_as_uint(v);
                float lof = v - __uint_as_float(u & 0xFFFF0000u);
                p[ht][r] = permhi(__float_as_uint(lof), u);
            }

        // GEMM2': shfl-transpose h1 into B2 frags; acc2 init with b2
        f32x4 acc2[2];
        acc2[0] = *(const f32x4*)(b2f + 4 * G);
        acc2[1] = *(const f32x4*)(b2f + 16 + 4 * G);
        const int srcbase = ((tid & 16) ? 32 : 0) + c;
        #pragma unroll
        for (int kt = 0; kt < 2; ++kt) {
            unsigned int q[8];
            #pragma unroll
            for (int half = 0; half < 2; ++half) {
                int src = srcbase + half * 16;
                #pragma unroll
                for (int r = 0; r < 4; ++r) {
                    unsigned int v0 = (unsigned int)__shfl((int)p[2 * kt][r], src, 64);
                    unsigned int v1 = (unsigned int)__shfl((int)p[2 * kt + 1][r], src, 64);
                    q[half * 4 + r] = (tid & 32) ? v1 : v0;
                }
            }
            CvtU4 BH, BL;
            #pragma unroll
            for (int j = 0; j < 4; ++j) {
                BH.u[j] = permlo(q[2 * j + 1], q[2 * j]);
                BL.u[j] = permhi(q[2 * j + 1], q[2 * j]);
            }
            #pragma unroll
            for (int jt = 0; jt < 2; ++jt) {
                acc2[jt] = __builtin_amdgcn_mfma_f32_16x16x32_bf16(A2h[jt][kt], BH.v, acc2[jt], 0, 0, 0);
                acc2[jt] = __builtin_amdgcn_mfma_f32_16x16x32_bf16(A2h[jt][kt], BL.v, acc2[jt], 0, 0, 0);
                acc2[jt] = __builtin_amdgcn_mfma_f32_16x16x32_bf16(A2l[jt][kt], BH.v, acc2[jt], 0, 0, 0);
            }
        }

        // scores: PReLU + W3-dot in-lane, xor-reduce
        float sv = 0.f;
        #pragma unroll
        for (int jt = 0; jt < 2; ++jt)
            #pragma unroll
            for (int r = 0; r < 4; ++r) {
                float v = acc2[jt][r];
                v = fmaxf(v, 0.f) + a2 * fminf(v, 0.f);
                sv = fmaf(v, w3f[jt * 16 + 4 * G + r], sv);
            }
        sv += __shfl_xor(sv, 16, 64);
        sv += __shfl_xor(sv, 32, 64);
        if ((tid & 48) == 0 && rr < NS) scf[rr] = sv + b3;
    }
    __syncthreads();

    // ---------- decay + mask + softmax ----------
    float scval = -INFINITY;
    if (tid < NS) {
        if (kmask[(size_t)b * NS + tid] != 0)
            scval = scf[tid] * __expf(0.1f * (float)(tid - (NS - 1)));
    }
    const int wid = tid >> 6, lane = tid & 63;
    float mx = scval;
    #pragma unroll
    for (int o = 32; o > 0; o >>= 1) mx = fmaxf(mx, __shfl_xor(mx, o, 64));
    if (lane == 0) wred[wid] = mx;
    __syncthreads();
    float M = fmaxf(fmaxf(wred[0], wred[1]), fmaxf(wred[2], wred[3]));
    float e = (M > -INFINITY && scval > -INFINITY) ? __expf(scval - M) : 0.f;
    float ssum = e;
    #pragma unroll
    for (int o = 32; o > 0; o >>= 1) ssum += __shfl_xor(ssum, o, 64);
    if (lane == 0) wred[4 + wid] = ssum;
    __syncthreads();
    float SUM = wred[4] + wred[5] + wred[6] + wred[7];
    float wv_ = (SUM > 0.f) ? (e / SUM) : 0.f;
    if (tid < NS) {
        wbf[tid] = wv_;
        out[(size_t)NB * ND + (size_t)b * NS + tid] = wv_;
    }
    __syncthreads();

    // ---------- pass 2: weighted_sum = w @ keys (float4, 8 groups x 25 rows) --
    float* part = (float*)(smem + U_W1HI);   // aliases dead W1hi: 8*128 floats
    {
        const int dq = tid & 31, sg = tid >> 5;
        const float* kp = keys + ((size_t)b * NS + sg * 25) * ND + dq * 4;
        float ax = 0.f, ay = 0.f, az = 0.f, aw = 0.f;
        #pragma unroll 5
        for (int i = 0; i < 25; ++i) {
            float ww = wbf[sg * 25 + i];
            float4 kv = *(const float4*)(kp + (size_t)i * ND);
            ax = fmaf(ww, kv.x, ax);
            ay = fmaf(ww, kv.y, ay);
            az = fmaf(ww, kv.z, az);
            aw = fmaf(ww, kv.w, aw);
        }
        *(float4*)(part + sg * 128 + dq * 4) = make_float4(ax, ay, az, aw);
    }
    __syncthreads();
    if (tid < 128) {
        float s = 0.f;
        #pragma unroll
        for (int g = 0; g < 8; ++g) s += part[g * 128 + tid];
        out[(size_t)b * ND + tid] = s;
    }
}

extern "C" void kernel_launch(void* const* d_in, const int* in_sizes, int n_in,
                              void* d_out, int out_size, void* d_ws, size_t ws_size,
                              hipStream_t stream) {
    (void)in_sizes; (void)n_in; (void)d_ws; (void)ws_size; (void)out_size;
    const float* query = (const float*)d_in[0];
    const float* keys  = (const float*)d_in[1];
    const int*   kmask = (const int*)d_in[2];
    const float* W1 = (const float*)d_in[3];
    const float* b1 = (const float*)d_in[4];
    const float* a1 = (const float*)d_in[5];
    const float* W2 = (const float*)d_in[6];
    const float* b2 = (const float*)d_in[7];
    const float* a2 = (const float*)d_in[8];
    const float* W3 = (const float*)d_in[9];
    const float* b3 = (const float*)d_in[10];
    float* out = (float*)d_out;

    hipLaunchKernelGGL(tdra_main, dim3(NB), dim3(256), 0, stream,
                       query, keys, kmask, W1, b1, a1, W2, b2, a2, W3, b3, out);
}

// Round 13
// 93.225 us; speedup vs baseline: 1.7925x; 1.1414x over previous
//
#include <hip/hip_runtime.h>
#include <math.h>

#define NB 2048
#define NS 200
#define ND 128

typedef __attribute__((ext_vector_type(8))) short bf16x8;
typedef __attribute__((ext_vector_type(4))) float f32x4;
typedef __attribute__((ext_vector_type(4))) unsigned short u16x4;

// LDS layout (u32 units)
#define U_W1HI  0                  // 64 x 136 u16 = 4352 u32 (aliased by pass-2 partials)
#define U_W1LO  4352               // 4352 u32
#define U_Q     8704               // 128 f32
#define U_BIAS  8832               // 64 f32
#define U_B2    8896               // 32 f32
#define U_W3    8928               // 32 f32
#define U_SC    8960               // 208 f32
#define U_WB    9168               // 208 f32
#define U_WRED  9376               // 16 f32
#define U_BP    9392               // 260 f32 (phase0 bias partials)
#define U_TOTAL 9652               // 38608 B -> 4 blocks/CU

extern "C" __global__ void __launch_bounds__(320, 5)
tdra_main(const float* __restrict__ query,
          const float* __restrict__ keys,
          const int*   __restrict__ kmask,
          const float* __restrict__ W1,
          const float* __restrict__ b1,
          const float* __restrict__ a1p,
          const float* __restrict__ W2,
          const float* __restrict__ b2,
          const float* __restrict__ a2p,
          const float* __restrict__ W3,
          const float* __restrict__ b3p,
          float* __restrict__ out)
{
    __shared__ __align__(16) unsigned int smem[U_TOTAL];
    unsigned short* W1hi = (unsigned short*)(smem + U_W1HI);
    unsigned short* W1lo = (unsigned short*)(smem + U_W1LO);
    float* qf    = (float*)(smem + U_Q);
    float* biasE = (float*)(smem + U_BIAS);
    float* b2f   = (float*)(smem + U_B2);
    float* w3f   = (float*)(smem + U_W3);
    float* scf   = (float*)(smem + U_SC);
    float* wbf   = (float*)(smem + U_WB);
    float* wred  = (float*)(smem + U_WRED);
    float* bpf   = (float*)(smem + U_BP);

    const int tid = threadIdx.x;
    const int b   = blockIdx.x;
    const float a1 = a1p[0];
    const float a2 = a2p[0];
    const float b3 = b3p[0];

    const int wv = tid >> 6;          // 0..4
    const int c  = tid & 15;
    const int G  = (tid >> 4) & 3;

    // ---------- Phase 0a: q, b2, W3 staging ----------
    if (tid < 32) {
        float4 qv = *(const float4*)(query + (size_t)b * ND + tid * 4);
        *(float4*)(qf + tid * 4) = qv;
    } else if (tid < 64) {
        b2f[tid - 32] = b2[tid - 32];
    } else if (tid < 96) {
        w3f[tid - 64] = W3[tid - 64];
    }

    // A2 = W2^T fragments straight from global (st-invariant, L2-hit)
    bf16x8 A2h[2][2], A2l[2][2];
    #pragma unroll
    for (int jt = 0; jt < 2; ++jt)
        #pragma unroll
        for (int kt = 0; kt < 2; ++kt)
            #pragma unroll
            for (int e = 0; e < 8; ++e) {
                float x = W2[(kt * 32 + 8 * G + e) * 32 + jt * 16 + c];
                unsigned int u  = __float_as_uint(x);
                unsigned int hb = u & 0xFFFF0000u;
                float lof = x - __uint_as_float(hb);
                A2h[jt][kt][e] = (short)(u >> 16);
                A2l[jt][kt][e] = (short)(__float_as_uint(lof) >> 16);
            }
    __syncthreads();

    // ---------- Phase 0b: W1 planes = split(W1a+W1d+q*W1c); bias partials ----
    {
        int h = tid & 63, dg = tid >> 6;       // 5 wave-groups
        #pragma unroll 1
        for (int dblk = dg; dblk < 32; dblk += 5) {
            u16x4 hi4, lo4;
            #pragma unroll
            for (int jj = 0; jj < 4; ++jj) {
                int d = dblk * 4 + jj;
                float qd = qf[d];
                float va = W1[d * 64 + h];
                float vc = W1[16384 + d * 64 + h];
                float vd = W1[24576 + d * 64 + h];
                float x  = va + vd + qd * vc;
                unsigned int u  = __float_as_uint(x);
                unsigned int hb = u & 0xFFFF0000u;
                float lof = x - __uint_as_float(hb);
                hi4[jj] = (unsigned short)(u >> 16);
                lo4[jj] = (unsigned short)(__float_as_uint(lof) >> 16);
            }
            *(u16x4*)(W1hi + h * 136 + dblk * 4) = hi4;
            *(u16x4*)(W1lo + h * 136 + dblk * 4) = lo4;
        }
        // bias partials: q @ (W1b - W1d), 4 quarters (wave 4 skips)
        if (dg < 4) {
            int qt = dg;
            const float* pb = W1 + (size_t)(128 + qt * 32) * 64 + h;
            const float* pd = W1 + (size_t)(384 + qt * 32) * 64 + h;
            float p = 0.f;
            #pragma unroll 8
            for (int i = 0; i < 32; ++i)
                p = fmaf(qf[qt * 32 + i], pb[i * 64] - pd[i * 64], p);
            bpf[qt * 65 + h] = p;
        }
    }
    __syncthreads();
    if (tid < 64)
        biasE[tid] = b1[tid] + bpf[tid] + bpf[65 + tid] + bpf[130 + tid] + bpf[195 + tid];
    __syncthreads();

    // ---------- Main: wave wv owns s-tiles st = wv, wv+5, wv+10 ----------
    #pragma unroll 1
    for (int st = wv; st < 13; st += 5) {
        const int rr = st * 16 + c;
        int row_ld = rr < 199 ? rr : 199;
        const float* kp = keys + ((size_t)b * NS + row_ld) * ND + 8 * G;

        // keys f32 -> B1 hi/lo frags (staggered halves)
        bf16x8 B1h[4], B1l[4];
        #pragma unroll
        for (int half = 0; half < 2; ++half) {
            float4 xs[4];
            #pragma unroll
            for (int q_ = 0; q_ < 2; ++q_) {
                xs[2 * q_]     = *(const float4*)(kp + (2 * half + q_) * 32);
                xs[2 * q_ + 1] = *(const float4*)(kp + (2 * half + q_) * 32 + 4);
            }
            #pragma unroll
            for (int q_ = 0; q_ < 2; ++q_) {
                int dt = 2 * half + q_;
                float fe[8] = {xs[2*q_].x, xs[2*q_].y, xs[2*q_].z, xs[2*q_].w,
                               xs[2*q_+1].x, xs[2*q_+1].y, xs[2*q_+1].z, xs[2*q_+1].w};
                #pragma unroll
                for (int e = 0; e < 8; ++e) {
                    unsigned int u  = __float_as_uint(fe[e]);
                    unsigned int hb = u & 0xFFFF0000u;
                    float lof = fe[e] - __uint_as_float(hb);
                    B1h[dt][e] = (short)(u >> 16);
                    B1l[dt][e] = (short)(__float_as_uint(lof) >> 16);
                }
            }
        }

        // GEMM1': acc1[ht] = bias + W1eff^T x K^T
        f32x4 acc1[4];
        #pragma unroll
        for (int ht = 0; ht < 4; ++ht)
            acc1[ht] = *(const f32x4*)(biasE + 16 * ht + 4 * G);
        #pragma unroll
        for (int dt = 0; dt < 4; ++dt) {
            #pragma unroll
            for (int ht = 0; ht < 4; ++ht) {
                int idx = (16 * ht + c) * 136 + 32 * dt + 8 * G;
                bf16x8 A1h = *(const bf16x8*)(W1hi + idx);
                bf16x8 A1l = *(const bf16x8*)(W1lo + idx);
                acc1[ht] = __builtin_amdgcn_mfma_f32_16x16x32_bf16(A1h, B1h[dt], acc1[ht], 0, 0, 0);
                acc1[ht] = __builtin_amdgcn_mfma_f32_16x16x32_bf16(A1h, B1l[dt], acc1[ht], 0, 0, 0);
                acc1[ht] = __builtin_amdgcn_mfma_f32_16x16x32_bf16(A1l, B1h[dt], acc1[ht], 0, 0, 0);
            }
        }

        // PReLU -> packed hi|lo h1
        unsigned int p[4][4];
        #pragma unroll
        for (int ht = 0; ht < 4; ++ht)
            #pragma unroll
            for (int r = 0; r < 4; ++r) {
                float v = acc1[ht][r];
                v = fmaxf(v, 0.f) + a1 * fminf(v, 0.f);
                unsigned int u  = __float_as_uint(v);
                unsigned int hb = u & 0xFFFF0000u;
                float lof = v - __uint_as_float(hb);
                p[ht][r] = (u >> 16) | (__float_as_uint(lof) & 0xFFFF0000u);
            }

        // GEMM2': shfl-transpose h1 into B2 frags; acc2 init with b2
        f32x4 acc2[2];
        acc2[0] = *(const f32x4*)(b2f + 4 * G);
        acc2[1] = *(const f32x4*)(b2f + 16 + 4 * G);
        const int srcbase = ((tid & 16) ? 32 : 0) + c;
        #pragma unroll
        for (int kt = 0; kt < 2; ++kt) {
            unsigned int q[8];
            #pragma unroll
            for (int half = 0; half < 2; ++half) {
                int src = srcbase + half * 16;
                #pragma unroll
                for (int r = 0; r < 4; ++r) {
                    unsigned int v0 = (unsigned int)__shfl((int)p[2 * kt][r], src, 64);
                    unsigned int v1 = (unsigned int)__shfl((int)p[2 * kt + 1][r], src, 64);
                    q[half * 4 + r] = (tid & 32) ? v1 : v0;
                }
            }
            bf16x8 B2h_, B2l_;
            #pragma unroll
            for (int e = 0; e < 8; ++e) {
                B2h_[e] = (short)(q[e] & 0xFFFFu);
                B2l_[e] = (short)(q[e] >> 16);
            }
            #pragma unroll
            for (int jt = 0; jt < 2; ++jt) {
                acc2[jt] = __builtin_amdgcn_mfma_f32_16x16x32_bf16(A2h[jt][kt], B2h_, acc2[jt], 0, 0, 0);
                acc2[jt] = __builtin_amdgcn_mfma_f32_16x16x32_bf16(A2h[jt][kt], B2l_, acc2[jt], 0, 0, 0);
                acc2[jt] = __builtin_amdgcn_mfma_f32_16x16x32_bf16(A2l[jt][kt], B2h_, acc2[jt], 0, 0, 0);
            }
        }

        // scores: PReLU + W3-dot in-lane, xor-reduce
        float sv = 0.f;
        #pragma unroll
        for (int jt = 0; jt < 2; ++jt)
            #pragma unroll
            for (int r = 0; r < 4; ++r) {
                float v = acc2[jt][r];
                v = fmaxf(v, 0.f) + a2 * fminf(v, 0.f);
                sv = fmaf(v, w3f[jt * 16 + 4 * G + r], sv);
            }
        sv += __shfl_xor(sv, 16, 64);
        sv += __shfl_xor(sv, 32, 64);
        if ((tid & 48) == 0 && rr < NS) scf[rr] = sv + b3;
    }
    __syncthreads();

    // ---------- decay + mask + softmax (5-wave block reduce) ----------
    float scval = -INFINITY;
    if (tid < NS) {
        if (kmask[(size_t)b * NS + tid] != 0)
            scval = scf[tid] * expf(0.1f * (float)(tid - (NS - 1)));
    }
    const int wid = tid >> 6, lane = tid & 63;
    float mx = scval;
    #pragma unroll
    for (int o = 32; o > 0; o >>= 1) mx = fmaxf(mx, __shfl_xor(mx, o, 64));
    if (lane == 0) wred[wid] = mx;
    __syncthreads();
    float M = wred[0];
    #pragma unroll
    for (int g = 1; g < 5; ++g) M = fmaxf(M, wred[g]);
    float e = (M > -INFINITY && scval > -INFINITY) ? expf(scval - M) : 0.f;
    float ssum = e;
    #pragma unroll
    for (int o = 32; o > 0; o >>= 1) ssum += __shfl_xor(ssum, o, 64);
    if (lane == 0) wred[8 + wid] = ssum;
    __syncthreads();
    float SUM = 0.f;
    #pragma unroll
    for (int g = 0; g < 5; ++g) SUM += wred[8 + g];
    float wv_ = (SUM > 0.f) ? (e / SUM) : 0.f;
    if (tid < NS) {
        wbf[tid] = wv_;
        out[(size_t)NB * ND + (size_t)b * NS + tid] = wv_;
    }
    __syncthreads();

    // ---------- pass 2: weighted_sum = w @ keys (10 groups x 20 rows) -------
    float* part = (float*)(smem + U_W1HI);   // aliases dead W1hi: 10*128 floats
    {
        const int dq = tid & 31, sg = tid >> 5;   // sg 0..9, rows sg*20..
        const float* kp = keys + ((size_t)b * NS + sg * 20) * ND + dq * 4;
        float ax = 0.f, ay = 0.f, az = 0.f, aw = 0.f;
        #pragma unroll 5
        for (int i = 0; i < 20; ++i) {
            float ww = wbf[sg * 20 + i];
            float4 kv = *(const float4*)(kp + (size_t)i * ND);
            ax = fmaf(ww, kv.x, ax);
            ay = fmaf(ww, kv.y, ay);
            az = fmaf(ww, kv.z, az);
            aw = fmaf(ww, kv.w, aw);
        }
        *(float4*)(part + sg * 128 + dq * 4) = make_float4(ax, ay, az, aw);
    }
    __syncthreads();
    if (tid < 128) {
        float s = 0.f;
        #pragma unroll
        for (int g = 0; g < 10; ++g) s += part[g * 128 + tid];
        out[(size_t)b * ND + tid] = s;
    }
}

extern "C" void kernel_launch(void* const* d_in, const int* in_sizes, int n_in,
                              void* d_out, int out_size, void* d_ws, size_t ws_size,
                              hipStream_t stream) {
    (void)in_sizes; (void)n_in; (void)d_ws; (void)ws_size; (void)out_size;
    const float* query = (const float*)d_in[0];
    const float* keys  = (const float*)d_in[1];
    const int*   kmask = (const int*)d_in[2];
    const float* W1 = (const float*)d_in[3];
    const float* b1 = (const float*)d_in[4];
    const float* a1 = (const float*)d_in[5];
    const float* W2 = (const float*)d_in[6];
    const float* b2 = (const float*)d_in[7];
    const float* a2 = (const float*)d_in[8];
    const float* W3 = (const float*)d_in[9];
    const float* b3 = (const float*)d_in[10];
    float* out = (float*)d_out;

    hipLaunchKernelGGL(tdra_main, dim3(NB), dim3(320), 0, stream,
                       query, keys, kmask, W1, b1, a1, W2, b2, a2, W3, b3, out);
}

// Round 14
// 81.306 us; speedup vs baseline: 2.0552x; 1.1466x over previous
//
#include <hip/hip_runtime.h>
#include <math.h>

#define NB 2048
#define NS 200
#define ND 128

typedef __attribute__((ext_vector_type(8))) short bf16x8;
typedef __attribute__((ext_vector_type(4))) float f32x4;
typedef __attribute__((ext_vector_type(4))) unsigned short u16x4;

// LDS layout (u32 units)
#define U_W1HI  0                  // 64 x 136 u16 = 4352 u32 (aliased by pass-2 partials)
#define U_W1LO  4352               // 4352 u32
#define U_Q     8704               // 128 f32
#define U_BIAS  8832               // 64 f32
#define U_B2    8896               // 32 f32
#define U_W3    8928               // 32 f32
#define U_SC    8960               // 208 f32
#define U_WB    9168               // 208 f32
#define U_WRED  9376               // 8 f32
#define U_BP    9384               // 260 f32
#define U_TOTAL 9644               // 38576 B -> 4 blocks/CU

extern "C" __global__ void __launch_bounds__(256, 4)
tdra_main(const float* __restrict__ query,
          const float* __restrict__ keys,
          const int*   __restrict__ kmask,
          const float* __restrict__ W1,
          const float* __restrict__ b1,
          const float* __restrict__ a1p,
          const float* __restrict__ W2,
          const float* __restrict__ b2,
          const float* __restrict__ a2p,
          const float* __restrict__ W3,
          const float* __restrict__ b3p,
          float* __restrict__ out)
{
    __shared__ __align__(16) unsigned int smem[U_TOTAL];
    unsigned short* W1hi = (unsigned short*)(smem + U_W1HI);
    unsigned short* W1lo = (unsigned short*)(smem + U_W1LO);
    float* qf    = (float*)(smem + U_Q);
    float* biasE = (float*)(smem + U_BIAS);
    float* b2f   = (float*)(smem + U_B2);
    float* w3f   = (float*)(smem + U_W3);
    float* scf   = (float*)(smem + U_SC);
    float* wbf   = (float*)(smem + U_WB);
    float* wred  = (float*)(smem + U_WRED);
    float* bpf   = (float*)(smem + U_BP);

    const int tid = threadIdx.x;
    const int b   = blockIdx.x;
    const float a1 = a1p[0];
    const float a2 = a2p[0];
    const float b3 = b3p[0];

    const int wv = tid >> 6;
    const int c  = tid & 15;
    const int G  = (tid >> 4) & 3;

    // ---------- Phase 0a: q, b2, W3 staging ----------
    if (tid < 32) {
        float4 qv = *(const float4*)(query + (size_t)b * ND + tid * 4);
        *(float4*)(qf + tid * 4) = qv;
    } else if (tid < 64) {
        b2f[tid - 32] = b2[tid - 32];
    } else if (tid < 96) {
        w3f[tid - 64] = W3[tid - 64];
    }

    // A2 = W2^T fragments straight from global (st-invariant, L2-hit)
    bf16x8 A2h[2][2], A2l[2][2];
    #pragma unroll
    for (int jt = 0; jt < 2; ++jt)
        #pragma unroll
        for (int kt = 0; kt < 2; ++kt)
            #pragma unroll
            for (int e = 0; e < 8; ++e) {
                float x = W2[(kt * 32 + 8 * G + e) * 32 + jt * 16 + c];
                unsigned int u  = __float_as_uint(x);
                unsigned int hb = u & 0xFFFF0000u;
                float lof = x - __uint_as_float(hb);
                A2h[jt][kt][e] = (short)(u >> 16);
                A2l[jt][kt][e] = (short)(__float_as_uint(lof) >> 16);
            }
    __syncthreads();

    // ---------- Phase 0b: W1 planes = split(W1a+W1d+q*W1c); bias partials ----
    {
        int h = tid & 63, dg = tid >> 6;
        #pragma unroll 2
        for (int i = 0; i < 8; ++i) {
            int dblk = dg * 8 + i;
            u16x4 hi4, lo4;
            #pragma unroll
            for (int jj = 0; jj < 4; ++jj) {
                int d = dblk * 4 + jj;
                float qd = qf[d];
                float va = W1[d * 64 + h];
                float vc = W1[16384 + d * 64 + h];
                float vd = W1[24576 + d * 64 + h];
                float x  = va + vd + qd * vc;
                unsigned int u  = __float_as_uint(x);
                unsigned int hb = u & 0xFFFF0000u;
                float lof = x - __uint_as_float(hb);
                hi4[jj] = (unsigned short)(u >> 16);
                lo4[jj] = (unsigned short)(__float_as_uint(lof) >> 16);
            }
            *(u16x4*)(W1hi + h * 136 + dblk * 4) = hi4;
            *(u16x4*)(W1lo + h * 136 + dblk * 4) = lo4;
        }
        int qt = dg;
        const float* pb = W1 + (size_t)(128 + qt * 32) * 64 + h;
        const float* pd = W1 + (size_t)(384 + qt * 32) * 64 + h;
        float p = 0.f;
        #pragma unroll 8
        for (int i = 0; i < 32; ++i)
            p = fmaf(qf[qt * 32 + i], pb[i * 64] - pd[i * 64], p);
        bpf[qt * 65 + h] = p;
    }
    __syncthreads();
    if (tid < 64)
        biasE[tid] = b1[tid] + bpf[tid] + bpf[65 + tid] + bpf[130 + tid] + bpf[195 + tid];
    __syncthreads();

    // ---------- Main: wave wv owns s-tiles st = wv, wv+4, wv+8, (wv+12) ------
    #pragma unroll 1
    for (int st = wv; st < 13; st += 4) {
        const int rr = st * 16 + c;
        int row_ld = rr < 199 ? rr : 199;
        const float* kp = keys + ((size_t)b * NS + row_ld) * ND + 8 * G;

        // keys f32 -> B1 hi/lo frags (staggered halves)
        bf16x8 B1h[4], B1l[4];
        #pragma unroll
        for (int half = 0; half < 2; ++half) {
            float4 xs[4];
            #pragma unroll
            for (int q_ = 0; q_ < 2; ++q_) {
                xs[2 * q_]     = *(const float4*)(kp + (2 * half + q_) * 32);
                xs[2 * q_ + 1] = *(const float4*)(kp + (2 * half + q_) * 32 + 4);
            }
            #pragma unroll
            for (int q_ = 0; q_ < 2; ++q_) {
                int dt = 2 * half + q_;
                float fe[8] = {xs[2*q_].x, xs[2*q_].y, xs[2*q_].z, xs[2*q_].w,
                               xs[2*q_+1].x, xs[2*q_+1].y, xs[2*q_+1].z, xs[2*q_+1].w};
                #pragma unroll
                for (int e = 0; e < 8; ++e) {
                    unsigned int u  = __float_as_uint(fe[e]);
                    unsigned int hb = u & 0xFFFF0000u;
                    float lof = fe[e] - __uint_as_float(hb);
                    B1h[dt][e] = (short)(u >> 16);
                    B1l[dt][e] = (short)(__float_as_uint(lof) >> 16);
                }
            }
        }

        // GEMM1': acc1[ht] = bias + W1eff^T x K^T  (setprio around MFMA cluster)
        f32x4 acc1[4];
        #pragma unroll
        for (int ht = 0; ht < 4; ++ht)
            acc1[ht] = *(const f32x4*)(biasE + 16 * ht + 4 * G);
        __builtin_amdgcn_s_setprio(1);
        #pragma unroll
        for (int dt = 0; dt < 4; ++dt) {
            #pragma unroll
            for (int ht = 0; ht < 4; ++ht) {
                int idx = (16 * ht + c) * 136 + 32 * dt + 8 * G;
                bf16x8 A1h = *(const bf16x8*)(W1hi + idx);
                bf16x8 A1l = *(const bf16x8*)(W1lo + idx);
                acc1[ht] = __builtin_amdgcn_mfma_f32_16x16x32_bf16(A1h, B1h[dt], acc1[ht], 0, 0, 0);
                acc1[ht] = __builtin_amdgcn_mfma_f32_16x16x32_bf16(A1h, B1l[dt], acc1[ht], 0, 0, 0);
                acc1[ht] = __builtin_amdgcn_mfma_f32_16x16x32_bf16(A1l, B1h[dt], acc1[ht], 0, 0, 0);
            }
        }
        __builtin_amdgcn_s_setprio(0);

        // PReLU -> packed hi|lo h1
        unsigned int p[4][4];
        #pragma unroll
        for (int ht = 0; ht < 4; ++ht)
            #pragma unroll
            for (int r = 0; r < 4; ++r) {
                float v = acc1[ht][r];
                v = fmaxf(v, 0.f) + a1 * fminf(v, 0.f);
                unsigned int u  = __float_as_uint(v);
                unsigned int hb = u & 0xFFFF0000u;
                float lof = v - __uint_as_float(hb);
                p[ht][r] = (u >> 16) | (__float_as_uint(lof) & 0xFFFF0000u);
            }

        // GEMM2': shfl-transpose h1 into B2 frags; acc2 init with b2
        f32x4 acc2[2];
        acc2[0] = *(const f32x4*)(b2f + 4 * G);
        acc2[1] = *(const f32x4*)(b2f + 16 + 4 * G);
        const int srcbase = ((tid & 16) ? 32 : 0) + c;
        #pragma unroll
        for (int kt = 0; kt < 2; ++kt) {
            unsigned int q[8];
            #pragma unroll
            for (int half = 0; half < 2; ++half) {
                int src = srcbase + half * 16;
                #pragma unroll
                for (int r = 0; r < 4; ++r) {
                    unsigned int v0 = (unsigned int)__shfl((int)p[2 * kt][r], src, 64);
                    unsigned int v1 = (unsigned int)__shfl((int)p[2 * kt + 1][r], src, 64);
                    q[half * 4 + r] = (tid & 32) ? v1 : v0;
                }
            }
            bf16x8 B2h_, B2l_;
            #pragma unroll
            for (int e = 0; e < 8; ++e) {
                B2h_[e] = (short)(q[e] & 0xFFFFu);
                B2l_[e] = (short)(q[e] >> 16);
            }
            __builtin_amdgcn_s_setprio(1);
            #pragma unroll
            for (int jt = 0; jt < 2; ++jt) {
                acc2[jt] = __builtin_amdgcn_mfma_f32_16x16x32_bf16(A2h[jt][kt], B2h_, acc2[jt], 0, 0, 0);
                acc2[jt] = __builtin_amdgcn_mfma_f32_16x16x32_bf16(A2h[jt][kt], B2l_, acc2[jt], 0, 0, 0);
                acc2[jt] = __builtin_amdgcn_mfma_f32_16x16x32_bf16(A2l[jt][kt], B2h_, acc2[jt], 0, 0, 0);
            }
            __builtin_amdgcn_s_setprio(0);
        }

        // scores: PReLU + W3-dot in-lane, xor-reduce
        float sv = 0.f;
        #pragma unroll
        for (int jt = 0; jt < 2; ++jt)
            #pragma unroll
            for (int r = 0; r < 4; ++r) {
                float v = acc2[jt][r];
                v = fmaxf(v, 0.f) + a2 * fminf(v, 0.f);
                sv = fmaf(v, w3f[jt * 16 + 4 * G + r], sv);
            }
        sv += __shfl_xor(sv, 16, 64);
        sv += __shfl_xor(sv, 32, 64);
        if ((tid & 48) == 0 && rr < NS) scf[rr] = sv + b3;
    }
    __syncthreads();

    // ---------- decay + mask + softmax ----------
    float scval = -INFINITY;
    if (tid < NS) {
        if (kmask[(size_t)b * NS + tid] != 0)
            scval = scf[tid] * __expf(0.1f * (float)(tid - (NS - 1)));
    }
    const int wid = tid >> 6, lane = tid & 63;
    float mx = scval;
    #pragma unroll
    for (int o = 32; o > 0; o >>= 1) mx = fmaxf(mx, __shfl_xor(mx, o, 64));
    if (lane == 0) wred[wid] = mx;
    __syncthreads();
    float M = fmaxf(fmaxf(wred[0], wred[1]), fmaxf(wred[2], wred[3]));
    float e = (M > -INFINITY && scval > -INFINITY) ? __expf(scval - M) : 0.f;
    float ssum = e;
    #pragma unroll
    for (int o = 32; o > 0; o >>= 1) ssum += __shfl_xor(ssum, o, 64);
    if (lane == 0) wred[4 + wid] = ssum;
    __syncthreads();
    float SUM = wred[4] + wred[5] + wred[6] + wred[7];
    float wv_ = (SUM > 0.f) ? (e / SUM) : 0.f;
    if (tid < NS) {
        wbf[tid] = wv_;
        out[(size_t)NB * ND + (size_t)b * NS + tid] = wv_;
    }
    __syncthreads();

    // ---------- pass 2: weighted_sum = w @ keys ----------
    {
        const int d = tid & 127, half = tid >> 7;
        const float* kp = keys + ((size_t)b * NS + half * 100) * ND + d;
        float pacc = 0.f;
        #pragma unroll 5
        for (int i = 0; i < 100; ++i)
            pacc = fmaf(wbf[half * 100 + i], kp[(size_t)i * ND], pacc);
        bpf[half * 128 + d] = pacc;
    }
    __syncthreads();
    if (tid < 128)
        out[(size_t)b * ND + tid] = bpf[tid] + bpf[128 + tid];
}

extern "C" void kernel_launch(void* const* d_in, const int* in_sizes, int n_in,
                              void* d_out, int out_size, void* d_ws, size_t ws_size,
                              hipStream_t stream) {
    (void)in_sizes; (void)n_in; (void)d_ws; (void)ws_size; (void)out_size;
    const float* query = (const float*)d_in[0];
    const float* keys  = (const float*)d_in[1];
    const int*   kmask = (const int*)d_in[2];
    const float* W1 = (const float*)d_in[3];
    const float* b1 = (const float*)d_in[4];
    const float* a1 = (const float*)d_in[5];
    const float* W2 = (const float*)d_in[6];
    const float* b2 = (const float*)d_in[7];
    const float* a2 = (const float*)d_in[8];
    const float* W3 = (const float*)d_in[9];
    const float* b3 = (const float*)d_in[10];
    float* out = (float*)d_out;

    hipLaunchKernelGGL(tdra_main, dim3(NB), dim3(256), 0, stream,
                       query, keys, kmask, W1, b1, a1, W2, b2, a2, W3, b3, out);
}